// Round 1
// baseline (136.923 us; speedup 1.0000x reference)
//
#include <hip/hip_runtime.h>
#include <math.h>

namespace {

constexpr int B  = 128;
constexpr int T  = 2048;
constexpr int F  = 512;
constexpr int OS = 20;
constexpr int OF = 42;
constexpr int NC = 10;
constexpr int NCHUNK  = 32;
constexpr int CHUNK_T = T / NCHUNK;   // 64
constexpr float BN_EPS = 1e-5f;

// ---------------------------------------------------------------------------
// Kernel A: streaming partial sums of y over t in [OS-1, fs) per (b, f).
// Grid (NCHUNK, B), 256 threads. Each block covers 64 t-rows; 2 rows per
// iteration (128 float4 lanes x 2 row-groups). Coalesced 16B/lane loads.
// ---------------------------------------------------------------------------
__global__ __launch_bounds__(256) void pool_partial_kernel(
    const float4* __restrict__ y4, const int* __restrict__ lengths,
    float4* __restrict__ mpart)
{
    const int chunk = blockIdx.x;
    const int b     = blockIdx.y;
    const int tid   = threadIdx.x;
    const int f4    = tid & 127;
    const int trow  = tid >> 7;
    const int fs    = lengths[b] - (OS - 1);
    const int t0    = chunk * CHUNK_T;

    const float4* __restrict__ base = y4 + (size_t)b * T * (F / 4) + f4;
    float4 acc = make_float4(0.f, 0.f, 0.f, 0.f);

    #pragma unroll 8
    for (int i = 0; i < CHUNK_T / 2; ++i) {
        const int t = t0 + 2 * i + trow;
        if (t >= OS - 1 && t < fs) {
            const float4 v = base[(size_t)t * (F / 4)];
            acc.x += v.x; acc.y += v.y; acc.z += v.z; acc.w += v.w;
        }
    }

    __shared__ float4 smem[F / 4];
    if (trow == 1) smem[f4] = acc;
    __syncthreads();
    if (trow == 0) {
        const float4 o = smem[f4];
        acc.x += o.x; acc.y += o.y; acc.z += o.z; acc.w += o.w;
        mpart[((size_t)b * NCHUNK + chunk) * (F / 4) + f4] = acc;
    }
}

// ---------------------------------------------------------------------------
// Kernel B: finish pooling. Reduce chunk partials -> M; gather 19 head and
// 19 tail rows; emit x transposed to [b][f][s] plus BN partials per (b,f).
// Grid (B), 512 threads (one per f).
// ---------------------------------------------------------------------------
__global__ __launch_bounds__(512) void pool_finish_kernel(
    const float* __restrict__ y, const int* __restrict__ lengths,
    const float* __restrict__ mpart, float* __restrict__ xpt,
    float* __restrict__ bnsum, float* __restrict__ bnsq)
{
    const int b  = blockIdx.x;
    const int f  = threadIdx.x;
    const int fs = lengths[b] - (OS - 1);

    float M = 0.f;
    #pragma unroll
    for (int c = 0; c < NCHUNK; ++c)
        M += mpart[((size_t)b * NCHUNK + c) * F + f];

    const float* __restrict__ yb = y + (size_t)b * T * F + f;
    float head[OS - 1], tail[OS - 1];
    #pragma unroll
    for (int j = 0; j < OS - 1; ++j) head[j] = yb[(size_t)j * F];
    #pragma unroll
    for (int j = 0; j < OS - 1; ++j) tail[j] = yb[(size_t)(fs + j) * F];

    float hs = 0.f;
    #pragma unroll
    for (int j = 0; j < OS - 1; ++j) hs += head[j];
    float tp = 0.f;

    const float inv = 1.f / (float)fs;
    float bs = 0.f, bq = 0.f;
    float* __restrict__ xo = xpt + ((size_t)b * F + f) * OS;

    #pragma unroll
    for (int s = 0; s < OS; ++s) {
        if (s > 0) { hs -= head[s - 1]; tp += tail[s - 1]; }
        const float x = (M + hs + tp) * inv;
        xo[s] = x;
        bs += x; bq += x * x;
    }
    bnsum[b * F + f] = bs;
    bnsq[b * F + f]  = bq;
}

// ---------------------------------------------------------------------------
// Kernel C: BN statistics over (b, s) per feature f -> folded scale/shift.
// Grid (F/64), 64 threads.
// ---------------------------------------------------------------------------
__global__ __launch_bounds__(64) void bn_stats_kernel(
    const float* __restrict__ bnsum, const float* __restrict__ bnsq,
    const float* __restrict__ gamma, const float* __restrict__ beta,
    float* __restrict__ scale, float* __restrict__ shift)
{
    const int f = blockIdx.x * 64 + threadIdx.x;
    float s = 0.f, q = 0.f;
    for (int b = 0; b < B; ++b) {
        s += bnsum[b * F + f];
        q += bnsq[b * F + f];
    }
    const float n    = (float)(B * OS);
    const float mu   = s / n;
    const float var  = q / n - mu * mu;
    const float rstd = rsqrtf(var + BN_EPS);
    const float sc   = rstd * gamma[f];
    scale[f] = sc;
    shift[f] = beta[f] - mu * sc;
}

// ---------------------------------------------------------------------------
// Kernel D: dense-net + linear head + softmax. One block per batch element.
// relu is idempotent, so d2..d5 are plain concatenations: c1..c5 write
// directly into the concat LDS buffer dd[210][20] (== flatten layout).
// ---------------------------------------------------------------------------
__device__ __forceinline__ void pconv_layer(
    int tid, int Cin, const float* __restrict__ W, const float* __restrict__ bias,
    const float* __restrict__ src, float* __restrict__ dst)
{
    if (tid < OF * 5) {                 // 210 active: (o, 4-wide l group)
        const int o  = tid / 5;
        const int l0 = (tid % 5) * 4;
        const float bv = bias[o];
        float4 acc = make_float4(bv, bv, bv, bv);
        const float* __restrict__ wrow = W + (size_t)o * Cin;
        for (int f = 0; f < Cin; ++f) {
            const float4 xv = *reinterpret_cast<const float4*>(src + f * OS + l0);
            const float  w  = wrow[f];
            acc.x = fmaf(w, xv.x, acc.x);
            acc.y = fmaf(w, xv.y, acc.y);
            acc.z = fmaf(w, xv.z, acc.z);
            acc.w = fmaf(w, xv.w, acc.w);
        }
        acc.x = fmaxf(acc.x, 0.f); acc.y = fmaxf(acc.y, 0.f);
        acc.z = fmaxf(acc.z, 0.f); acc.w = fmaxf(acc.w, 0.f);
        *reinterpret_cast<float4*>(dst + o * OS + l0) = acc;
    }
}

__global__ __launch_bounds__(256) void mlp_kernel(
    const float* __restrict__ xpt,
    const float* __restrict__ scale, const float* __restrict__ shift,
    const float* __restrict__ W1, const float* __restrict__ b1,
    const float* __restrict__ W2, const float* __restrict__ b2,
    const float* __restrict__ W3, const float* __restrict__ b3,
    const float* __restrict__ W4, const float* __restrict__ b4,
    const float* __restrict__ W5, const float* __restrict__ b5,
    const float* __restrict__ Wlin, const float* __restrict__ blin,
    float* __restrict__ out)
{
    const int b   = blockIdx.x;
    const int tid = threadIdx.x;
    __shared__ float xs[F * OS];          // 40 KB, layout [f][l]
    __shared__ float dd[5 * OF * OS];     // 16.8 KB, layout [c][l] == flatten order
    __shared__ float red[4];
    __shared__ float lg[NC];

    // Load pooled x (already [b][f][s]) and apply folded BN.
    const float* __restrict__ xin = xpt + (size_t)b * F * OS;
    for (int i = tid; i < F * OS; i += 256) {
        const int f = i / OS;
        xs[i] = fmaf(xin[i], scale[f], shift[f]);
    }
    __syncthreads();

    pconv_layer(tid, F,      W1, b1, xs, dd);              __syncthreads();
    pconv_layer(tid, OF,     W2, b2, dd, dd + 1 * OF * OS); __syncthreads();
    pconv_layer(tid, 2 * OF, W3, b3, dd, dd + 2 * OF * OS); __syncthreads();
    pconv_layer(tid, 3 * OF, W4, b4, dd, dd + 3 * OF * OS); __syncthreads();
    pconv_layer(tid, 4 * OF, W5, b5, dd, dd + 4 * OF * OS); __syncthreads();

    // Linear head: logits[k] = dd_flat . Wlin[k] + blin[k]
    float pk[NC];
    #pragma unroll
    for (int k = 0; k < NC; ++k) pk[k] = 0.f;
    for (int j = tid; j < 5 * OF * OS / 4; j += 256) {     // 1050 float4s
        const float4 v = *reinterpret_cast<const float4*>(dd + j * 4);
        #pragma unroll
        for (int k = 0; k < NC; ++k) {
            const float4 w = *reinterpret_cast<const float4*>(
                Wlin + (size_t)k * (5 * OF * OS) + j * 4);
            pk[k] += v.x * w.x + v.y * w.y + v.z * w.z + v.w * w.w;
        }
    }
    #pragma unroll
    for (int k = 0; k < NC; ++k) {
        float p = pk[k];
        #pragma unroll
        for (int off = 32; off > 0; off >>= 1) p += __shfl_down(p, off);
        if ((tid & 63) == 0) red[tid >> 6] = p;
        __syncthreads();
        if (tid == 0) lg[k] = red[0] + red[1] + red[2] + red[3] + blin[k];
        __syncthreads();
    }

    if (tid == 0) {
        float m = lg[0];
        #pragma unroll
        for (int k = 1; k < NC; ++k) m = fmaxf(m, lg[k]);
        float e[NC]; float s = 0.f;
        #pragma unroll
        for (int k = 0; k < NC; ++k) { e[k] = expf(lg[k] - m); s += e[k]; }
        const float is = 1.f / s;
        #pragma unroll
        for (int k = 0; k < NC; ++k) out[b * NC + k] = e[k] * is;
    }
}

} // anonymous namespace

extern "C" void kernel_launch(void* const* d_in, const int* in_sizes, int n_in,
                              void* d_out, int out_size, void* d_ws, size_t ws_size,
                              hipStream_t stream)
{
    const float* y       = (const float*)d_in[0];
    const int*   lengths = (const int*)d_in[1];
    const float* gamma   = (const float*)d_in[2];
    const float* beta    = (const float*)d_in[3];
    const float* W1      = (const float*)d_in[4];
    const float* b1      = (const float*)d_in[5];
    const float* W2      = (const float*)d_in[6];
    const float* b2      = (const float*)d_in[7];
    const float* W3      = (const float*)d_in[8];
    const float* b3      = (const float*)d_in[9];
    const float* W4      = (const float*)d_in[10];
    const float* b4      = (const float*)d_in[11];
    const float* W5      = (const float*)d_in[12];
    const float* b5      = (const float*)d_in[13];
    const float* Wlin    = (const float*)d_in[14];
    const float* blin    = (const float*)d_in[15];
    float* out = (float*)d_out;

    // Workspace layout (floats): ~14.2 MB total.
    float* ws    = (float*)d_ws;
    float* mpart = ws;                                  // B*NCHUNK*F   = 2,097,152
    float* xpt   = mpart + (size_t)B * NCHUNK * F;      // B*F*OS      = 1,310,720
    float* bnsum = xpt + (size_t)B * F * OS;            // B*F         = 65,536
    float* bnsq  = bnsum + (size_t)B * F;               // B*F         = 65,536
    float* scale = bnsq + (size_t)B * F;                // F
    float* shift = scale + F;                           // F

    pool_partial_kernel<<<dim3(NCHUNK, B), 256, 0, stream>>>(
        (const float4*)y, lengths, (float4*)mpart);
    pool_finish_kernel<<<dim3(B), 512, 0, stream>>>(
        y, lengths, mpart, xpt, bnsum, bnsq);
    bn_stats_kernel<<<dim3(F / 64), 64, 0, stream>>>(
        bnsum, bnsq, gamma, beta, scale, shift);
    mlp_kernel<<<dim3(B), 256, 0, stream>>>(
        xpt, scale, shift, W1, b1, W2, b2, W3, b3, W4, b4, W5, b5,
        Wlin, blin, out);
}

// Round 3
// 117.988 us; speedup vs baseline: 1.1605x; 1.1605x over previous
//
#include <hip/hip_runtime.h>
#include <math.h>

namespace {

constexpr int B  = 128;
constexpr int T  = 2048;
constexpr int F  = 512;
constexpr int OS = 20;
constexpr int OF = 42;
constexpr int NC = 10;
constexpr int NCHUNK  = 32;
constexpr int CHUNK_T = T / NCHUNK;   // 64
constexpr float BN_EPS = 1e-5f;

typedef float vfloat4 __attribute__((ext_vector_type(4)));

// ---------------------------------------------------------------------------
// Kernel A: streaming partial sums of y over t in [OS-1, fs) per (b, f).
// Grid (NCHUNK, B), 256 threads. Range-clipped loop, no per-iteration branch,
// nontemporal 16B/lane loads (y is read-once).
// ---------------------------------------------------------------------------
__global__ __launch_bounds__(256) void pool_partial_kernel(
    const vfloat4* __restrict__ y4, const int* __restrict__ lengths,
    vfloat4* __restrict__ mpart)
{
    const int chunk = blockIdx.x;
    const int b     = blockIdx.y;
    const int tid   = threadIdx.x;
    const int f4    = tid & 127;
    const int trow  = tid >> 7;
    const int fs    = lengths[b] - (OS - 1);
    const int t0    = chunk * CHUNK_T;
    const int lo    = (t0 > OS - 1) ? t0 : OS - 1;
    const int hi    = (t0 + CHUNK_T < fs) ? t0 + CHUNK_T : fs;

    const vfloat4* __restrict__ base = y4 + (size_t)b * T * (F / 4) + f4;
    vfloat4 acc = {0.f, 0.f, 0.f, 0.f};

    #pragma unroll 4
    for (int t = lo + trow; t < hi; t += 2) {
        const vfloat4 v = __builtin_nontemporal_load(&base[(size_t)t * (F / 4)]);
        acc += v;
    }

    __shared__ vfloat4 smem[F / 4];
    if (trow == 1) smem[f4] = acc;
    __syncthreads();
    if (trow == 0) {
        acc += smem[f4];
        mpart[((size_t)b * NCHUNK + chunk) * (F / 4) + f4] = acc;
    }
}

// ---------------------------------------------------------------------------
// Kernel B: finish pooling. Reduce chunk partials -> M; gather 19 head and
// 19 tail rows; emit x transposed to [b][f][s] plus BN partials per (b,f).
// Grid (B), 512 threads (one per f).
// ---------------------------------------------------------------------------
__global__ __launch_bounds__(512) void pool_finish_kernel(
    const float* __restrict__ y, const int* __restrict__ lengths,
    const float* __restrict__ mpart, float* __restrict__ xpt,
    float* __restrict__ bnsum, float* __restrict__ bnsq)
{
    const int b  = blockIdx.x;
    const int f  = threadIdx.x;
    const int fs = lengths[b] - (OS - 1);

    float M = 0.f;
    #pragma unroll
    for (int c = 0; c < NCHUNK; ++c)
        M += mpart[((size_t)b * NCHUNK + c) * F + f];

    const float* __restrict__ yb = y + (size_t)b * T * F + f;
    float head[OS - 1], tail[OS - 1];
    #pragma unroll
    for (int j = 0; j < OS - 1; ++j) head[j] = yb[(size_t)j * F];
    #pragma unroll
    for (int j = 0; j < OS - 1; ++j) tail[j] = yb[(size_t)(fs + j) * F];

    float hs = 0.f;
    #pragma unroll
    for (int j = 0; j < OS - 1; ++j) hs += head[j];
    float tp = 0.f;

    const float inv = 1.f / (float)fs;
    float bs = 0.f, bq = 0.f;
    float* __restrict__ xo = xpt + ((size_t)b * F + f) * OS;

    #pragma unroll
    for (int s = 0; s < OS; ++s) {
        if (s > 0) { hs -= head[s - 1]; tp += tail[s - 1]; }
        const float x = (M + hs + tp) * inv;
        xo[s] = x;
        bs += x; bq += x * x;
    }
    bnsum[b * F + f] = bs;
    bnsq[b * F + f]  = bq;
}

// ---------------------------------------------------------------------------
// Kernel C: BN finalize (redundantly per block, deterministic) + dense-net +
// linear head + softmax. One block per batch element, 256 threads.
// relu idempotence => d2..d5 are plain concatenations: c1..c5 write directly
// into the concat LDS buffer dd[210][20] (== flatten layout).
// ---------------------------------------------------------------------------
__device__ __forceinline__ void pconv_layer(
    int tid, int Cin, const float* __restrict__ W, const float* __restrict__ bias,
    const float* __restrict__ src, float* __restrict__ dst)
{
    if (tid < OF * 5) {                 // 210 active: (o, 4-wide l group)
        const int o  = tid / 5;
        const int l0 = (tid % 5) * 4;
        const float bv = bias[o];
        float4 acc = make_float4(bv, bv, bv, bv);
        const float* __restrict__ wrow = W + (size_t)o * Cin;
        for (int f = 0; f < Cin; ++f) {
            const float4 xv = *reinterpret_cast<const float4*>(src + f * OS + l0);
            const float  w  = wrow[f];
            acc.x = fmaf(w, xv.x, acc.x);
            acc.y = fmaf(w, xv.y, acc.y);
            acc.z = fmaf(w, xv.z, acc.z);
            acc.w = fmaf(w, xv.w, acc.w);
        }
        acc.x = fmaxf(acc.x, 0.f); acc.y = fmaxf(acc.y, 0.f);
        acc.z = fmaxf(acc.z, 0.f); acc.w = fmaxf(acc.w, 0.f);
        *reinterpret_cast<float4*>(dst + o * OS + l0) = acc;
    }
}

__global__ __launch_bounds__(256) void mlp_kernel(
    const float* __restrict__ xpt,
    const float* __restrict__ bnsum, const float* __restrict__ bnsq,
    const float* __restrict__ gamma, const float* __restrict__ beta,
    const float* __restrict__ W1, const float* __restrict__ b1,
    const float* __restrict__ W2, const float* __restrict__ b2,
    const float* __restrict__ W3, const float* __restrict__ b3,
    const float* __restrict__ W4, const float* __restrict__ b4,
    const float* __restrict__ W5, const float* __restrict__ b5,
    const float* __restrict__ Wlin, const float* __restrict__ blin,
    float* __restrict__ out)
{
    const int b   = blockIdx.x;
    const int tid = threadIdx.x;
    __shared__ float xs[F * OS];          // 40 KB, layout [f][l]
    __shared__ float dd[5 * OF * OS];     // 16.8 KB, layout [c][l] == flatten order
    __shared__ float sscale[F];           // 2 KB
    __shared__ float sshift[F];           // 2 KB
    __shared__ float red[NC][4];
    __shared__ float lgs[NC];

    // BN finalize: per-f reduction over b (L2-resident, identical in every block).
    for (int f = tid; f < F; f += 256) {
        float s = 0.f, q = 0.f;
        #pragma unroll 8
        for (int bb = 0; bb < B; ++bb) {
            s += bnsum[bb * F + f];
            q += bnsq[bb * F + f];
        }
        const float n    = (float)(B * OS);
        const float mu   = s / n;
        const float var  = q / n - mu * mu;
        const float sc   = rsqrtf(var + BN_EPS) * gamma[f];
        sscale[f] = sc;
        sshift[f] = beta[f] - mu * sc;
    }
    __syncthreads();

    // Load pooled x (already [b][f][s]) and apply folded BN.
    const float* __restrict__ xin = xpt + (size_t)b * F * OS;
    for (int i = tid; i < F * OS; i += 256) {
        const int f = i / OS;
        xs[i] = fmaf(xin[i], sscale[f], sshift[f]);
    }
    __syncthreads();

    pconv_layer(tid, F,      W1, b1, xs, dd);               __syncthreads();
    pconv_layer(tid, OF,     W2, b2, dd, dd + 1 * OF * OS); __syncthreads();
    pconv_layer(tid, 2 * OF, W3, b3, dd, dd + 2 * OF * OS); __syncthreads();
    pconv_layer(tid, 3 * OF, W4, b4, dd, dd + 3 * OF * OS); __syncthreads();
    pconv_layer(tid, 4 * OF, W5, b5, dd, dd + 4 * OF * OS); __syncthreads();

    // Linear head: logits[k] = dd_flat . Wlin[k] + blin[k]
    float pk[NC];
    #pragma unroll
    for (int k = 0; k < NC; ++k) pk[k] = 0.f;
    for (int j = tid; j < 5 * OF * OS / 4; j += 256) {     // 1050 float4s
        const float4 v = *reinterpret_cast<const float4*>(dd + j * 4);
        #pragma unroll
        for (int k = 0; k < NC; ++k) {
            const float4 w = *reinterpret_cast<const float4*>(
                Wlin + (size_t)k * (5 * OF * OS) + j * 4);
            pk[k] += v.x * w.x + v.y * w.y + v.z * w.z + v.w * w.w;
        }
    }
    const int lane = tid & 63;
    const int wid  = tid >> 6;
    #pragma unroll
    for (int k = 0; k < NC; ++k) {
        float p = pk[k];
        #pragma unroll
        for (int off = 32; off > 0; off >>= 1) p += __shfl_down(p, off);
        if (lane == 0) red[k][wid] = p;
    }
    __syncthreads();
    if (tid < NC)
        lgs[tid] = red[tid][0] + red[tid][1] + red[tid][2] + red[tid][3] + blin[tid];
    __syncthreads();

    if (tid == 0) {
        float m = lgs[0];
        #pragma unroll
        for (int k = 1; k < NC; ++k) m = fmaxf(m, lgs[k]);
        float e[NC]; float s = 0.f;
        #pragma unroll
        for (int k = 0; k < NC; ++k) { e[k] = expf(lgs[k] - m); s += e[k]; }
        const float is = 1.f / s;
        #pragma unroll
        for (int k = 0; k < NC; ++k) out[b * NC + k] = e[k] * is;
    }
}

} // anonymous namespace

extern "C" void kernel_launch(void* const* d_in, const int* in_sizes, int n_in,
                              void* d_out, int out_size, void* d_ws, size_t ws_size,
                              hipStream_t stream)
{
    const float* y       = (const float*)d_in[0];
    const int*   lengths = (const int*)d_in[1];
    const float* gamma   = (const float*)d_in[2];
    const float* beta    = (const float*)d_in[3];
    const float* W1      = (const float*)d_in[4];
    const float* b1      = (const float*)d_in[5];
    const float* W2      = (const float*)d_in[6];
    const float* b2      = (const float*)d_in[7];
    const float* W3      = (const float*)d_in[8];
    const float* b3      = (const float*)d_in[9];
    const float* W4      = (const float*)d_in[10];
    const float* b4      = (const float*)d_in[11];
    const float* W5      = (const float*)d_in[12];
    const float* b5      = (const float*)d_in[13];
    const float* Wlin    = (const float*)d_in[14];
    const float* blin    = (const float*)d_in[15];
    float* out = (float*)d_out;

    // Workspace layout (floats): ~14.2 MB total.
    float* ws    = (float*)d_ws;
    float* mpart = ws;                                  // B*NCHUNK*F   = 2,097,152
    float* xpt   = mpart + (size_t)B * NCHUNK * F;      // B*F*OS      = 1,310,720
    float* bnsum = xpt + (size_t)B * F * OS;            // B*F         = 65,536
    float* bnsq  = bnsum + (size_t)B * F;               // B*F         = 65,536

    pool_partial_kernel<<<dim3(NCHUNK, B), 256, 0, stream>>>(
        (const vfloat4*)y, lengths, (vfloat4*)mpart);
    pool_finish_kernel<<<dim3(B), 512, 0, stream>>>(
        y, lengths, mpart, xpt, bnsum, bnsq);
    mlp_kernel<<<dim3(B), 256, 0, stream>>>(
        xpt, bnsum, bnsq, gamma, beta, W1, b1, W2, b2, W3, b3, W4, b4, W5, b5,
        Wlin, blin, out);
}

// Round 4
// 116.165 us; speedup vs baseline: 1.1787x; 1.0157x over previous
//
#include <hip/hip_runtime.h>
#include <math.h>

namespace {

constexpr int B  = 128;
constexpr int T  = 2048;
constexpr int F  = 512;
constexpr int OS = 20;
constexpr int OF = 42;
constexpr int NC = 10;
constexpr int NCHUNK  = 16;
constexpr int CHUNK_T = T / NCHUNK;   // 128
constexpr float BN_EPS = 1e-5f;

typedef float vfloat4 __attribute__((ext_vector_type(4)));

// ---------------------------------------------------------------------------
// Kernel A: streaming partial sums of y over t in [OS-1, fs) per (b, f).
// Grid (NCHUNK, B) = 2048 blocks, 256 threads. Range-clipped loop, unroll 8,
// nontemporal 16B/lane loads (y is read-once; keep L2 for mpart).
// ---------------------------------------------------------------------------
__global__ __launch_bounds__(256) void pool_partial_kernel(
    const vfloat4* __restrict__ y4, const int* __restrict__ lengths,
    vfloat4* __restrict__ mpart)
{
    const int chunk = blockIdx.x;
    const int b     = blockIdx.y;
    const int tid   = threadIdx.x;
    const int f4    = tid & 127;
    const int trow  = tid >> 7;
    const int fs    = lengths[b] - (OS - 1);
    const int t0    = chunk * CHUNK_T;
    const int lo    = (t0 > OS - 1) ? t0 : OS - 1;
    const int hi    = (t0 + CHUNK_T < fs) ? t0 + CHUNK_T : fs;

    const vfloat4* __restrict__ base = y4 + (size_t)b * T * (F / 4) + f4;
    vfloat4 acc = {0.f, 0.f, 0.f, 0.f};

    #pragma unroll 8
    for (int t = lo + trow; t < hi; t += 2) {
        const vfloat4 v = __builtin_nontemporal_load(&base[(size_t)t * (F / 4)]);
        acc += v;
    }

    __shared__ vfloat4 smem[F / 4];
    if (trow == 1) smem[f4] = acc;
    __syncthreads();
    if (trow == 0) {
        acc += smem[f4];
        mpart[((size_t)b * NCHUNK + chunk) * (F / 4) + f4] = acc;
    }
}

// ---------------------------------------------------------------------------
// Kernel B: finish pooling. Reduce chunk partials -> M; gather 19 head and
// 19 tail rows; emit x transposed to [b][f][s] (float4 stores) plus BN
// partials per (b,f). Grid (B), 512 threads (one per f).
// ---------------------------------------------------------------------------
__global__ __launch_bounds__(512) void pool_finish_kernel(
    const float* __restrict__ y, const int* __restrict__ lengths,
    const float* __restrict__ mpart, float* __restrict__ xpt,
    float* __restrict__ bnsum, float* __restrict__ bnsq)
{
    const int b  = blockIdx.x;
    const int f  = threadIdx.x;
    const int fs = lengths[b] - (OS - 1);

    float M = 0.f;
    #pragma unroll
    for (int c = 0; c < NCHUNK; ++c)
        M += mpart[((size_t)b * NCHUNK + c) * F + f];

    const float* __restrict__ yb = y + (size_t)b * T * F + f;
    float head[OS - 1], tail[OS - 1];
    #pragma unroll
    for (int j = 0; j < OS - 1; ++j) head[j] = yb[(size_t)j * F];
    #pragma unroll
    for (int j = 0; j < OS - 1; ++j) tail[j] = yb[(size_t)(fs + j) * F];

    float hs = 0.f;
    #pragma unroll
    for (int j = 0; j < OS - 1; ++j) hs += head[j];
    float tp = 0.f;

    const float inv = 1.f / (float)fs;
    float bs = 0.f, bq = 0.f;
    float xv[OS];

    #pragma unroll
    for (int s = 0; s < OS; ++s) {
        if (s > 0) { hs -= head[s - 1]; tp += tail[s - 1]; }
        const float x = (M + hs + tp) * inv;
        xv[s] = x;
        bs += x; bq += x * x;
    }

    vfloat4* __restrict__ xo4 =
        reinterpret_cast<vfloat4*>(xpt + ((size_t)b * F + f) * OS);
    #pragma unroll
    for (int q = 0; q < OS / 4; ++q) {
        vfloat4 v = {xv[4 * q], xv[4 * q + 1], xv[4 * q + 2], xv[4 * q + 3]};
        xo4[q] = v;
    }
    bnsum[b * F + f] = bs;
    bnsq[b * F + f]  = bq;
}

// ---------------------------------------------------------------------------
// Kernel C: BN finalize (redundantly per block, deterministic) + dense-net +
// linear head + softmax. One block per batch element, 256 threads.
// relu idempotence => d2..d5 are plain concatenations: c1..c5 write directly
// into the concat LDS buffer dd[210][20] (== flatten layout).
// ---------------------------------------------------------------------------
__device__ __forceinline__ void pconv_layer(
    int tid, int Cin, const float* __restrict__ W, const float* __restrict__ bias,
    const float* __restrict__ src, float* __restrict__ dst)
{
    if (tid < OF * 5) {                 // 210 active: (o, 4-wide l group)
        const int o  = tid / 5;
        const int l0 = (tid % 5) * 4;
        const float bv = bias[o];
        float4 acc = make_float4(bv, bv, bv, bv);
        const float* __restrict__ wrow = W + (size_t)o * Cin;
        for (int f = 0; f < Cin; ++f) {
            const float4 xv = *reinterpret_cast<const float4*>(src + f * OS + l0);
            const float  w  = wrow[f];
            acc.x = fmaf(w, xv.x, acc.x);
            acc.y = fmaf(w, xv.y, acc.y);
            acc.z = fmaf(w, xv.z, acc.z);
            acc.w = fmaf(w, xv.w, acc.w);
        }
        acc.x = fmaxf(acc.x, 0.f); acc.y = fmaxf(acc.y, 0.f);
        acc.z = fmaxf(acc.z, 0.f); acc.w = fmaxf(acc.w, 0.f);
        *reinterpret_cast<float4*>(dst + o * OS + l0) = acc;
    }
}

__global__ __launch_bounds__(256) void mlp_kernel(
    const float* __restrict__ xpt,
    const float* __restrict__ bnsum, const float* __restrict__ bnsq,
    const float* __restrict__ gamma, const float* __restrict__ beta,
    const float* __restrict__ W1, const float* __restrict__ b1,
    const float* __restrict__ W2, const float* __restrict__ b2,
    const float* __restrict__ W3, const float* __restrict__ b3,
    const float* __restrict__ W4, const float* __restrict__ b4,
    const float* __restrict__ W5, const float* __restrict__ b5,
    const float* __restrict__ Wlin, const float* __restrict__ blin,
    float* __restrict__ out)
{
    const int b   = blockIdx.x;
    const int tid = threadIdx.x;
    __shared__ float xs[F * OS];          // 40 KB, layout [f][l]
    __shared__ float dd[5 * OF * OS];     // 16.8 KB, layout [c][l] == flatten order
    __shared__ float sscale[F];           // 2 KB
    __shared__ float sshift[F];           // 2 KB
    __shared__ float red[NC][4];
    __shared__ float lgs[NC];

    // BN finalize: per-f reduction over b (L2-resident, identical in every block).
    for (int f = tid; f < F; f += 256) {
        float s = 0.f, q = 0.f;
        #pragma unroll 8
        for (int bb = 0; bb < B; ++bb) {
            s += bnsum[bb * F + f];
            q += bnsq[bb * F + f];
        }
        const float n    = (float)(B * OS);
        const float mu   = s / n;
        const float var  = q / n - mu * mu;
        const float sc   = rsqrtf(var + BN_EPS) * gamma[f];
        sscale[f] = sc;
        sshift[f] = beta[f] - mu * sc;
    }
    __syncthreads();

    // Load pooled x (already [b][f][s]) and apply folded BN.
    const float* __restrict__ xin = xpt + (size_t)b * F * OS;
    for (int i = tid; i < F * OS; i += 256) {
        const int f = i / OS;
        xs[i] = fmaf(xin[i], sscale[f], sshift[f]);
    }
    __syncthreads();

    pconv_layer(tid, F,      W1, b1, xs, dd);               __syncthreads();
    pconv_layer(tid, OF,     W2, b2, dd, dd + 1 * OF * OS); __syncthreads();
    pconv_layer(tid, 2 * OF, W3, b3, dd, dd + 2 * OF * OS); __syncthreads();
    pconv_layer(tid, 3 * OF, W4, b4, dd, dd + 3 * OF * OS); __syncthreads();
    pconv_layer(tid, 4 * OF, W5, b5, dd, dd + 4 * OF * OS); __syncthreads();

    // Linear head: logits[k] = dd_flat . Wlin[k] + blin[k]
    float pk[NC];
    #pragma unroll
    for (int k = 0; k < NC; ++k) pk[k] = 0.f;
    for (int j = tid; j < 5 * OF * OS / 4; j += 256) {     // 1050 float4s
        const float4 v = *reinterpret_cast<const float4*>(dd + j * 4);
        #pragma unroll
        for (int k = 0; k < NC; ++k) {
            const float4 w = *reinterpret_cast<const float4*>(
                Wlin + (size_t)k * (5 * OF * OS) + j * 4);
            pk[k] += v.x * w.x + v.y * w.y + v.z * w.z + v.w * w.w;
        }
    }
    const int lane = tid & 63;
    const int wid  = tid >> 6;
    #pragma unroll
    for (int k = 0; k < NC; ++k) {
        float p = pk[k];
        #pragma unroll
        for (int off = 32; off > 0; off >>= 1) p += __shfl_down(p, off);
        if (lane == 0) red[k][wid] = p;
    }
    __syncthreads();
    if (tid < NC)
        lgs[tid] = red[tid][0] + red[tid][1] + red[tid][2] + red[tid][3] + blin[tid];
    __syncthreads();

    if (tid == 0) {
        float m = lgs[0];
        #pragma unroll
        for (int k = 1; k < NC; ++k) m = fmaxf(m, lgs[k]);
        float e[NC]; float s = 0.f;
        #pragma unroll
        for (int k = 0; k < NC; ++k) { e[k] = expf(lgs[k] - m); s += e[k]; }
        const float is = 1.f / s;
        #pragma unroll
        for (int k = 0; k < NC; ++k) out[b * NC + k] = e[k] * is;
    }
}

} // anonymous namespace

extern "C" void kernel_launch(void* const* d_in, const int* in_sizes, int n_in,
                              void* d_out, int out_size, void* d_ws, size_t ws_size,
                              hipStream_t stream)
{
    const float* y       = (const float*)d_in[0];
    const int*   lengths = (const int*)d_in[1];
    const float* gamma   = (const float*)d_in[2];
    const float* beta    = (const float*)d_in[3];
    const float* W1      = (const float*)d_in[4];
    const float* b1      = (const float*)d_in[5];
    const float* W2      = (const float*)d_in[6];
    const float* b2      = (const float*)d_in[7];
    const float* W3      = (const float*)d_in[8];
    const float* b3      = (const float*)d_in[9];
    const float* W4      = (const float*)d_in[10];
    const float* b4      = (const float*)d_in[11];
    const float* W5      = (const float*)d_in[12];
    const float* b5      = (const float*)d_in[13];
    const float* Wlin    = (const float*)d_in[14];
    const float* blin    = (const float*)d_in[15];
    float* out = (float*)d_out;

    // Workspace layout (floats): ~7 MB total.
    float* ws    = (float*)d_ws;
    float* mpart = ws;                                  // B*NCHUNK*F = 1,048,576
    float* xpt   = mpart + (size_t)B * NCHUNK * F;      // B*F*OS     = 1,310,720
    float* bnsum = xpt + (size_t)B * F * OS;            // B*F        = 65,536
    float* bnsq  = bnsum + (size_t)B * F;               // B*F        = 65,536

    pool_partial_kernel<<<dim3(NCHUNK, B), 256, 0, stream>>>(
        (const vfloat4*)y, lengths, (vfloat4*)mpart);
    pool_finish_kernel<<<dim3(B), 512, 0, stream>>>(
        y, lengths, mpart, xpt, bnsum, bnsq);
    mlp_kernel<<<dim3(B), 256, 0, stream>>>(
        xpt, bnsum, bnsq, gamma, beta, W1, b1, W2, b2, W3, b3, W4, b4, W5, b5,
        Wlin, blin, out);
}